// Round 2
// baseline (181.919 us; speedup 1.0000x reference)
//
#include <hip/hip_runtime.h>

// CLIPTextEmbeddings: out[s, :] = token_weight[input_ids[s], :] + position_weight[position_ids[s], :]
// SEQ=77, DIM=768. Pure gather+add, memory-bound (trivially small: ~0.7 MB total traffic).
// One block per row; 192 threads * float4 = 768 floats per row. Fully coalesced.
// 192 threads = 3 full waves of 64 — no partial-wave waste.

#define SEQ 77
#define DIM 768
#define T_PER_ROW (DIM / 4)   // 192 threads, each handling one float4

__global__ void __launch_bounds__(T_PER_ROW)
clip_embed_kernel(const int* __restrict__ input_ids,
                  const int* __restrict__ position_ids,
                  const float* __restrict__ token_weight,
                  const float* __restrict__ position_weight,
                  float* __restrict__ out) {
    const int row = blockIdx.x;     // 0..SEQ-1
    const int t   = threadIdx.x;    // 0..191

    const int tok = input_ids[row];
    const int pos = position_ids[row];

    const float4 va = reinterpret_cast<const float4*>(token_weight    + (size_t)tok * DIM)[t];
    const float4 vb = reinterpret_cast<const float4*>(position_weight + (size_t)pos * DIM)[t];

    float4 r;
    r.x = va.x + vb.x;
    r.y = va.y + vb.y;
    r.z = va.z + vb.z;
    r.w = va.w + vb.w;

    reinterpret_cast<float4*>(out + (size_t)row * DIM)[t] = r;
}

extern "C" void kernel_launch(void* const* d_in, const int* in_sizes, int n_in,
                              void* d_out, int out_size, void* d_ws, size_t ws_size,
                              hipStream_t stream) {
    const int*   input_ids       = (const int*)d_in[0];
    const int*   position_ids    = (const int*)d_in[1];
    const float* token_weight    = (const float*)d_in[2];
    const float* position_weight = (const float*)d_in[3];
    float*       out             = (float*)d_out;

    clip_embed_kernel<<<SEQ, T_PER_ROW, 0, stream>>>(
        input_ids, position_ids, token_weight, position_weight, out);
}